// Round 7
// baseline (126.346 us; speedup 1.0000x reference)
//
#include <hip/hip_runtime.h>
#include <hip/hip_bf16.h>

#define B_ 2
#define T_ 1024
#define D_ 1024
#define H_ 8
#define DEPTH_ 5
#define DH_ 128

typedef short s16x8 __attribute__((ext_vector_type(8)));
typedef short s16x4 __attribute__((ext_vector_type(4)));
typedef float f32x4 __attribute__((ext_vector_type(4)));
typedef float f32x2 __attribute__((ext_vector_type(2)));

__device__ inline short f2bf(float f) {
  __hip_bfloat16 h = __float2bfloat16(f);
  return *reinterpret_cast<short*>(&h);
}

#define MFMA16(a, b, c) __builtin_amdgcn_mfma_f32_16x16x32_bf16(a, b, c, 0, 0, 0)

// packed fp32 (VOP3P, full-rate on gfx950): d = a*b+c / a*b / a+b per 32-bit half
__device__ __forceinline__ f32x2 pk_fma2(f32x2 a, f32x2 b, f32x2 c) {
  f32x2 d;
  asm("v_pk_fma_f32 %0, %1, %2, %3" : "=v"(d) : "v"(a), "v"(b), "v"(c));
  return d;
}
__device__ __forceinline__ f32x2 pk_mul2(f32x2 a, f32x2 b) {
  f32x2 d;
  asm("v_pk_mul_f32 %0, %1, %2" : "=v"(d) : "v"(a), "v"(b));
  return d;
}
__device__ __forceinline__ f32x2 pk_add2(f32x2 a, f32x2 b) {
  f32x2 d;
  asm("v_pk_add_f32 %0, %1, %2" : "=v"(d) : "v"(a), "v"(b));
  return d;
}

// global -> LDS async copy, 16B/lane. LDS dest = wave-uniform base + lane*16.
typedef __attribute__((address_space(3))) unsigned int lds_u32_t;
typedef __attribute__((address_space(1))) unsigned int glb_u32_t;
__device__ __forceinline__ void glds16(const void* g, void* l) {
  __builtin_amdgcn_global_load_lds((const glb_u32_t*)g, (lds_u32_t*)l, 16, 0,
                                   0);
}

// compiler fence + hw barrier (raw: does NOT drain vmcnt like __syncthreads)
#define BARRIER()                     \
  {                                   \
    asm volatile("" ::: "memory");    \
    __builtin_amdgcn_s_barrier();     \
    asm volatile("" ::: "memory");    \
  }

// contiguous-chunk XCD swizzle: consecutive logical ids stay on ONE XCD
// (dispatch round-robins blockIdx across the 8 XCDs). Requires nwg%8==0.
__device__ __forceinline__ int xcd_swz(int bid, int nwg) {
  int cpx = nwg >> 3;
  return (bid & 7) * cpx + (bid >> 3);
}

// -------------------------------------------------------------------------
// Prep (one launch, grid (16,16,3), 256 threads) — r6-proven form:
//  z=0: Wv[K][N] -> WBt rows 0..1023 (bf16 [n][k])
//  z=1: Wo -> Wot (bf16 [n][k])
//  z=2: x fp32 -> xb bf16 (streaming); blocks 0..3 also scatter
//       Wp[1024][40] -> WBt rows 1024..1087 (rows >=40 zeroed).
// Streaming / no inter-block reuse -> no swizzle (T1 transfer null).
// -------------------------------------------------------------------------
__global__ __launch_bounds__(256) void prep_kernel(
    const float* __restrict__ Wv, const float* __restrict__ Wo,
    const float* __restrict__ Wp, const float* __restrict__ x,
    short* __restrict__ WBt, short* __restrict__ Wot,
    short* __restrict__ xb) {
  int tid = threadIdx.x;
  if (blockIdx.z < 2) {
    const float* W = blockIdx.z ? Wo : Wv;
    short* Wt = blockIdx.z ? Wot : WBt;
    __shared__ float tile[64][65];
    int k0 = blockIdx.y * 64, n0 = blockIdx.x * 64;
#pragma unroll
    for (int i = 0; i < 4; ++i) {
      int idx = tid + i * 256;
      int r = idx >> 4, c4 = (idx & 15) * 4;
      float4 v = *(const float4*)&W[(size_t)(k0 + r) * D_ + n0 + c4];
      tile[r][c4 + 0] = v.x;
      tile[r][c4 + 1] = v.y;
      tile[r][c4 + 2] = v.z;
      tile[r][c4 + 3] = v.w;
    }
    __syncthreads();
#pragma unroll
    for (int j = 0; j < 2; ++j) {
      int idx = tid + j * 256;
      int n = idx >> 3, k8 = (idx & 7) * 8;
      s16x8 outv;
#pragma unroll
      for (int jj = 0; jj < 8; ++jj) outv[jj] = f2bf(tile[k8 + jj][n]);
      *(s16x8*)&Wt[(size_t)(n0 + n) * D_ + k0 + k8] = outv;
    }
  } else {
    int bid = blockIdx.y * 16 + blockIdx.x;  // 0..255
#pragma unroll
    for (int c = 0; c < 4; ++c) {
      size_t idx = (size_t)bid * 8192 + c * 2048 + tid * 8;
      float4 f0 = *(const float4*)&x[idx];
      float4 f1 = *(const float4*)&x[idx + 4];
      s16x8 v;
      v[0] = f2bf(f0.x); v[1] = f2bf(f0.y);
      v[2] = f2bf(f0.z); v[3] = f2bf(f0.w);
      v[4] = f2bf(f1.x); v[5] = f2bf(f1.y);
      v[6] = f2bf(f1.z); v[7] = f2bf(f1.w);
      *(s16x8*)&xb[idx] = v;
    }
    if (bid < 4) {  // Wp rows of WBt
#pragma unroll
      for (int it = 0; it < 8; ++it) {
        int item = bid * 2048 + it * 256 + tid;  // 0..8191
        int row = item >> 7, k8 = (item & 127) * 8;
        s16x8 v;
        if (row < H_ * DEPTH_) {
#pragma unroll
          for (int j = 0; j < 8; ++j)
            v[j] = f2bf(Wp[(size_t)(k8 + j) * (H_ * DEPTH_) + row]);
        } else {
#pragma unroll
          for (int j = 0; j < 8; ++j) v[j] = 0;
        }
        *(s16x8*)&WBt[(size_t)(1024 + row) * D_ + k8] = v;
      }
    }
  }
}

// -------------------------------------------------------------------------
// MFMA bf16 GEMM, 64x64 tile, BK=64 dbuf + counted vmcnt(4) (R3-proven),
// 1D grid + contiguous-chunk XCD swizzle (R6-proven). Unchanged from R6.
// -------------------------------------------------------------------------
template <int MODE, int NX>
__global__ __launch_bounds__(256) void gemm128(
    const short* __restrict__ A, const short* __restrict__ Bt,
    float* __restrict__ Cf, short* __restrict__ Vt,
    const float* __restrict__ bp, float* __restrict__ paths_t) {
  __shared__ short As[2][64 * 64];  // 2 x 8 KB
  __shared__ short Bs[2][64 * 64];  // 2 x 8 KB
  const int K = D_;
  int tid = threadIdx.x;
  int swz = xcd_swz(blockIdx.x, NX * 32);
  int bm = (swz / NX) << 6, bn = (swz % NX) << 6;
  int w = tid >> 6, lane = tid & 63;
  int wm = (w >> 1) * 32, wn = (w & 1) * 32;
  int g = lane >> 4, fr = lane & 15;
  f32x4 acc[2][2] = {};

  // staging source addressing: per 1KB chunk lane l covers row l>>3,
  // source colgroup (l&7)^(l>>3) (XOR swizzle, same for every chunk).
  int r8 = lane >> 3;
  int scg = (lane & 7) ^ r8;
  const short* Asrc[2];
  const short* Bsrc[2];
#pragma unroll
  for (int i = 0; i < 2; ++i) {
    Asrc[i] = A + (size_t)(bm + w * 16 + i * 8 + r8) * K + scg * 8;
    Bsrc[i] = Bt + (size_t)(bn + w * 16 + i * 8 + r8) * K + scg * 8;
  }

#define STAGE(BUF, K0)                                    \
  {                                                       \
    glds16(Asrc[0] + (K0), &As[BUF][(w * 16 + 0) * 64]);  \
    glds16(Asrc[1] + (K0), &As[BUF][(w * 16 + 8) * 64]);  \
    glds16(Bsrc[0] + (K0), &Bs[BUF][(w * 16 + 0) * 64]);  \
    glds16(Bsrc[1] + (K0), &Bs[BUF][(w * 16 + 8) * 64]);  \
  }

#define COMPUTE(BUF)                                                   \
  {                                                                    \
    _Pragma("unroll") for (int ks = 0; ks < 2; ++ks) {                 \
      int slot = ((ks * 4 + g) ^ (fr & 7)) * 8;                        \
      s16x8 a0 = *(const s16x8*)&As[BUF][(wm + fr) * 64 + slot];       \
      s16x8 a1 = *(const s16x8*)&As[BUF][(wm + 16 + fr) * 64 + slot];  \
      s16x8 b0 = *(const s16x8*)&Bs[BUF][(wn + fr) * 64 + slot];       \
      s16x8 b1 = *(const s16x8*)&Bs[BUF][(wn + 16 + fr) * 64 + slot];  \
      acc[0][0] = MFMA16(a0, b0, acc[0][0]);                           \
      acc[0][1] = MFMA16(a0, b1, acc[0][1]);                           \
      acc[1][0] = MFMA16(a1, b0, acc[1][0]);                           \
      acc[1][1] = MFMA16(a1, b1, acc[1][1]);                           \
    }                                                                  \
  }

  // K-loop: 16 K-steps of 64, dbuf, prefetch depth 1.
  // After STAGE(next): <=8 glds outstanding; vmcnt(4) -> cur tile landed.
  STAGE(0, 0);
  for (int kt = 0; kt < 16; kt += 2) {
    BARRIER();  // readers of buf1 (COMPUTE(1) of prev pair) done
    STAGE(1, (kt + 1) * 64);
    asm volatile("s_waitcnt vmcnt(4)" ::: "memory");  // tile kt landed
    BARRIER();
    COMPUTE(0);
    BARRIER();  // readers of buf0 done
    if (kt + 2 < 16) {
      STAGE(0, (kt + 2) * 64);
      asm volatile("s_waitcnt vmcnt(4)" ::: "memory");  // tile kt+1 landed
    } else {
      asm volatile("s_waitcnt vmcnt(0)" ::: "memory");
    }
    BARRIER();
    COMPUTE(1);
  }
#undef STAGE
#undef COMPUTE

  int col = lane & 15, rbase = (lane >> 4) * 4;
  if (MODE == 0) {
#pragma unroll
    for (int mi = 0; mi < 2; ++mi)
#pragma unroll
      for (int ni = 0; ni < 2; ++ni)
#pragma unroll
        for (int r = 0; r < 4; ++r)
          Cf[(size_t)(bm + wm + mi * 16 + rbase + r) * D_ + bn + wn +
             ni * 16 + col] = acc[mi][ni][r];
  } else if (bn < 1024) {
    // V epilogue: bf16, transposed [bh][dh][t]
#pragma unroll
    for (int mi = 0; mi < 2; ++mi)
#pragma unroll
      for (int ni = 0; ni < 2; ++ni) {
        int m = bm + wm + mi * 16 + rbase;  // t start (4 consecutive)
        int n = bn + wn + ni * 16 + col;    // dh col
        int b = m >> 10, t = m & (T_ - 1);
        int h = n >> 7, dh = n & (DH_ - 1);
        s16x4 v4;
#pragma unroll
        for (int r = 0; r < 4; ++r) v4[r] = f2bf(acc[mi][ni][r]);
        *(s16x4*)&Vt[((size_t)((b * H_ + h) * DH_ + dh)) * T_ + t] = v4;
      }
  } else {
    // paths epilogue: sigmoid(z + bp), fp32, (B,H,T,DEPTH)
#pragma unroll
    for (int ni = 0; ni < 2; ++ni) {
      int pn = wn + ni * 16 + col;  // 0..63
      if (pn < H_ * DEPTH_) {
        float bias = bp[pn];
        int h = pn / DEPTH_, d = pn % DEPTH_;
#pragma unroll
        for (int mi = 0; mi < 2; ++mi)
#pragma unroll
          for (int r = 0; r < 4; ++r) {
            int m = bm + wm + mi * 16 + rbase + r;
            int b = m >> 10, t = m & (T_ - 1);
            float pv = 1.f / (1.f + __expf(-(acc[mi][ni][r] + bias)));
            paths_t[(((size_t)(b * H_ + h) * T_ + t) * DEPTH_) + d] = pv;
          }
      }
    }
  }
}

// -------------------------------------------------------------------------
// Fused causal p-adic attention, MFMA P.V.  512 threads / 8 waves.
// KT=128: 9 k-tiles per block-pair (qt/4 + (31-qt)/4 + 2 == 9 for all qt).
// NEW (guide Common-mistake #7): V is NOT LDS-staged. With bh-major XCD
// swizzle the 256 KB Vt slice is L2-resident, and the [bh][dh][t] layout
// makes each lane's MFMA B-fragment 16 CONTIGUOUS global bytes:
// vv[ks] = Vt[bh][w*16+fr][k0+ks*32+g*8 ..+7]. Fragments are loaded
// directly to VGPRs right after the first barrier (older than the pk
// loads in the vmcnt FIFO -> land under the ~500cy sim phase). Removes
// 74 MB of glds DMA, the per-tile vmcnt(0) drain, and 32 KB LDS.
// SIM via packed fp32: agree = (2pq-1)*pk + (1-pq), packed over q-row pairs.
// -------------------------------------------------------------------------
#define LS2 136

__global__ __launch_bounds__(512) void attn_kernel(
    const float* __restrict__ paths_t, const short* __restrict__ Vt,
    short* __restrict__ ctxb) {
  int swz = xcd_swz(blockIdx.x, 256);
  int bh = swz >> 4;  // 0..15 (bh-major: 16 sharers contiguous)
  int bx = swz & 15;  // 0..15
  int b = bh >> 3, h = bh & 7;
  int w = threadIdx.x >> 6, lane = threadIdx.x & 63;
  int g = lane >> 4, fr = lane & 15;

  __shared__ short Ss[32 * LS2];  // [q][k] padded 136, ~8.5 KB
  __shared__ float lsum_s[32];

  const float* pb = paths_t + (size_t)bh * T_ * DEPTH_;
  const short* vb = Vt + (size_t)bh * DH_ * T_;
  const short* vrow = vb + (size_t)(w * 16 + fr) * T_ + g * 8;  // lane's V row

  for (int half = 0; half < 2; ++half) {
    int qt = half ? (31 - bx) : bx;
    int q0 = qt * 32;
    int nkt = (qt >> 2) + 1;  // KT=128 tiles; pair total = 9 always

    // per-half q-row coefficient pairs: agree = c1*pk + c0,
    // c1 = 2*pq-1, c0 = 1-pq, packed over (j0,j1) / (j2,j3).
    f32x2 c1_[2][DEPTH_], c0_[2][DEPTH_];
#pragma unroll
    for (int jp = 0; jp < 2; ++jp) {
      const float* qr0 = pb + (size_t)(q0 + w * 4 + jp * 2) * DEPTH_;
      const float* qr1 = qr0 + DEPTH_;
#pragma unroll
      for (int d = 0; d < DEPTH_; ++d) {
        float p0 = qr0[d], p1 = qr1[d];
        c1_[jp][d] = (f32x2){2.f * p0 - 1.f, 2.f * p1 - 1.f};
        c0_[jp][d] = (f32x2){1.f - p0, 1.f - p1};
      }
    }
    f32x4 acc[2] = {{0.f, 0.f, 0.f, 0.f}, {0.f, 0.f, 0.f, 0.f}};
    float part[4] = {};
    const f32x2 one2 = {1.f, 1.f};

    for (int kt = 0; kt < nkt; ++kt) {
      int k0 = kt * 128;
      __syncthreads();  // prev PV readers of Ss done
      // V fragments for this tile: direct global (L2-hit), issued FIRST so
      // they are oldest in the vmcnt queue -> fully landed by PV time.
      s16x8 vv[4];
#pragma unroll
      for (int ks = 0; ks < 4; ++ks)
        vv[ks] = *(const s16x8*)&vrow[k0 + ks * 32];
      // key-path loads
      int kA = k0 + lane, kB = k0 + 64 + lane;
      const float* krA = pb + (size_t)kA * DEPTH_;
      const float* krB = pb + (size_t)kB * DEPTH_;
      float pkA[DEPTH_], pkB[DEPTH_];
#pragma unroll
      for (int d = 0; d < DEPTH_; ++d) {
        pkA[d] = krA[d];
        pkB[d] = krB[d];
      }
      // splat k-path values into packed pairs
      f32x2 bkA[DEPTH_], bkB[DEPTH_];
#pragma unroll
      for (int d = 0; d < DEPTH_; ++d) {
        bkA[d] = (f32x2){pkA[d], pkA[d]};
        bkB[d] = (f32x2){pkB[d], pkB[d]};
      }
#pragma unroll
      for (int jp = 0; jp < 2; ++jp) {
        {  // column A (k = kA)
          f32x2 a0 = pk_fma2(c1_[jp][0], bkA[0], c0_[jp][0]);
          f32x2 a1 = pk_fma2(c1_[jp][1], bkA[1], c0_[jp][1]);
          f32x2 a2 = pk_fma2(c1_[jp][2], bkA[2], c0_[jp][2]);
          f32x2 a3 = pk_fma2(c1_[jp][3], bkA[3], c0_[jp][3]);
          f32x2 a4 = pk_fma2(c1_[jp][4], bkA[4], c0_[jp][4]);
          f32x2 t4 = pk_add2(a4, one2);
          f32x2 t3 = pk_fma2(a3, t4, one2);
          f32x2 t2 = pk_fma2(a2, t3, one2);
          f32x2 t1 = pk_fma2(a1, t2, one2);
          f32x2 s2 = pk_mul2(a0, t1);
#pragma unroll
          for (int jj = 0; jj < 2; ++jj) {
            int j = jp * 2 + jj;
            int qg = q0 + w * 4 + j;
            float wv = (kA <= qg) ? __expf(s2[jj] * 0.2f) : 0.f;
            part[j] += wv;
            Ss[(w * 4 + j) * LS2 + lane] = f2bf(wv);
          }
        }
        {  // column B (k = kB)
          f32x2 a0 = pk_fma2(c1_[jp][0], bkB[0], c0_[jp][0]);
          f32x2 a1 = pk_fma2(c1_[jp][1], bkB[1], c0_[jp][1]);
          f32x2 a2 = pk_fma2(c1_[jp][2], bkB[2], c0_[jp][2]);
          f32x2 a3 = pk_fma2(c1_[jp][3], bkB[3], c0_[jp][3]);
          f32x2 a4 = pk_fma2(c1_[jp][4], bkB[4], c0_[jp][4]);
          f32x2 t4 = pk_add2(a4, one2);
          f32x2 t3 = pk_fma2(a3, t4, one2);
          f32x2 t2 = pk_fma2(a2, t3, one2);
          f32x2 t1 = pk_fma2(a1, t2, one2);
          f32x2 s2 = pk_mul2(a0, t1);
#pragma unroll
          for (int jj = 0; jj < 2; ++jj) {
            int j = jp * 2 + jj;
            int qg = q0 + w * 4 + j;
            float wv = (kB <= qg) ? __expf(s2[jj] * 0.2f) : 0.f;
            part[j] += wv;
            Ss[(w * 4 + j) * LS2 + 64 + lane] = f2bf(wv);
          }
        }
      }
      __syncthreads();  // Ss writes visible to all waves (lgkm drained)
      // P @ V via MFMA: wave covers dh [16*w, 16*w+16); 4 ks steps of k32
#pragma unroll
      for (int ks = 0; ks < 4; ++ks) {
        int ko = ks * 32 + g * 8;
        s16x8 sa0 = *(const s16x8*)&Ss[fr * LS2 + ko];
        s16x8 sa1 = *(const s16x8*)&Ss[(16 + fr) * LS2 + ko];
        acc[0] = MFMA16(sa0, vv[ks], acc[0]);
        acc[1] = MFMA16(sa1, vv[ks], acc[1]);
      }
    }
    // reduce per-q row sums across the wave's 64 lanes (each lane holds 2 k)
#pragma unroll
    for (int j = 0; j < 4; ++j) {
      float s = part[j];
#pragma unroll
      for (int off = 32; off >= 1; off >>= 1) s += __shfl_xor(s, off, 64);
      if (lane == j) lsum_s[w * 4 + j] = s;
    }
    __syncthreads();
    // epilogue: normalize, write bf16 ctx
    int col = fr, rbase = g * 4;
#pragma unroll
    for (int qt2 = 0; qt2 < 2; ++qt2)
#pragma unroll
      for (int r = 0; r < 4; ++r) {
        int ql = qt2 * 16 + rbase + r;
        int dh = w * 16 + col;
        float val = acc[qt2][r] / lsum_s[ql];
        ctxb[(size_t)(b * T_ + q0 + ql) * D_ + h * DH_ + dh] = f2bf(val);
      }
    __syncthreads();  // protect lsum_s before next half
  }
}

// -------------------------------------------------------------------------
extern "C" void kernel_launch(void* const* d_in, const int* in_sizes, int n_in,
                              void* d_out, int out_size, void* d_ws,
                              size_t ws_size, hipStream_t stream) {
  const float* x = (const float*)d_in[0];
  const float* Wp = (const float*)d_in[1];
  const float* bp = (const float*)d_in[2];
  const float* Wv = (const float*)d_in[3];
  const float* Wo = (const float*)d_in[4];
  float* out = (float*)d_out;

  char* ws = (char*)d_ws;
  float* paths_t = (float*)ws;           //   327,680 B
  short* Vt = (short*)(ws + 327680);     // 4,194,304 B bf16 [bh][dh][t]
  short* WBt = (short*)(ws + 4521984);   // 2,228,224 B bf16 [1088][1024]
  short* Wot = (short*)(ws + 6750208);   // 2,097,152 B bf16 [1024][1024]
  short* ctxb = (short*)(ws + 8847360);  // 4,194,304 B bf16 [2048][1024]
  short* xb = (short*)(ws + 13041664);   // 4,194,304 B bf16 [2048][1024]
  // total ~17.2 MB

  prep_kernel<<<dim3(16, 16, 3), 256, 0, stream>>>(Wv, Wo, Wp, x, WBt, Wot,
                                                   xb);
  gemm128<1, 17><<<dim3(17 * 32), 256, 0, stream>>>(xb, WBt, nullptr, Vt, bp,
                                                    paths_t);
  attn_kernel<<<dim3(256), 512, 0, stream>>>(paths_t, Vt, ctxb);
  gemm128<0, 16><<<dim3(16 * 32), 256, 0, stream>>>(ctxb, Wot, out, nullptr,
                                                    nullptr, nullptr);
}

// Round 8
// 123.413 us; speedup vs baseline: 1.0238x; 1.0238x over previous
//
#include <hip/hip_runtime.h>
#include <hip/hip_bf16.h>

#define B_ 2
#define T_ 1024
#define D_ 1024
#define H_ 8
#define DEPTH_ 5
#define DH_ 128

typedef short s16x8 __attribute__((ext_vector_type(8)));
typedef short s16x4 __attribute__((ext_vector_type(4)));
typedef float f32x4 __attribute__((ext_vector_type(4)));
typedef float f32x2 __attribute__((ext_vector_type(2)));

__device__ inline short f2bf(float f) {
  __hip_bfloat16 h = __float2bfloat16(f);
  return *reinterpret_cast<short*>(&h);
}

#define MFMA16(a, b, c) __builtin_amdgcn_mfma_f32_16x16x32_bf16(a, b, c, 0, 0, 0)

// packed fp32 (VOP3P, full-rate on gfx950): d = a*b+c / a*b / a+b per 32-bit half
__device__ __forceinline__ f32x2 pk_fma2(f32x2 a, f32x2 b, f32x2 c) {
  f32x2 d;
  asm("v_pk_fma_f32 %0, %1, %2, %3" : "=v"(d) : "v"(a), "v"(b), "v"(c));
  return d;
}
__device__ __forceinline__ f32x2 pk_mul2(f32x2 a, f32x2 b) {
  f32x2 d;
  asm("v_pk_mul_f32 %0, %1, %2" : "=v"(d) : "v"(a), "v"(b));
  return d;
}
__device__ __forceinline__ f32x2 pk_add2(f32x2 a, f32x2 b) {
  f32x2 d;
  asm("v_pk_add_f32 %0, %1, %2" : "=v"(d) : "v"(a), "v"(b));
  return d;
}

// global -> LDS async copy, 16B/lane. LDS dest = wave-uniform base + lane*16.
typedef __attribute__((address_space(3))) unsigned int lds_u32_t;
typedef __attribute__((address_space(1))) unsigned int glb_u32_t;
__device__ __forceinline__ void glds16(const void* g, void* l) {
  __builtin_amdgcn_global_load_lds((const glb_u32_t*)g, (lds_u32_t*)l, 16, 0,
                                   0);
}

// compiler fence + hw barrier (raw: does NOT drain vmcnt like __syncthreads)
#define BARRIER()                     \
  {                                   \
    asm volatile("" ::: "memory");    \
    __builtin_amdgcn_s_barrier();     \
    asm volatile("" ::: "memory");    \
  }

// contiguous-chunk XCD swizzle: consecutive logical ids stay on ONE XCD
// (dispatch round-robins blockIdx across the 8 XCDs). Requires nwg%8==0.
__device__ __forceinline__ int xcd_swz(int bid, int nwg) {
  int cpx = nwg >> 3;
  return (bid & 7) * cpx + (bid >> 3);
}

// -------------------------------------------------------------------------
// Prep (one launch, grid (16,16,3), 256 threads) — r6-proven form:
//  z=0: Wv[K][N] -> WBt rows 0..1023 (bf16 [n][k])
//  z=1: Wo -> Wot (bf16 [n][k])
//  z=2: x fp32 -> xb bf16 (streaming); blocks 0..3 also scatter
//       Wp[1024][40] -> WBt rows 1024..1087 (rows >=40 zeroed).
// Streaming / no inter-block reuse -> no swizzle (T1 transfer null).
// -------------------------------------------------------------------------
__global__ __launch_bounds__(256) void prep_kernel(
    const float* __restrict__ Wv, const float* __restrict__ Wo,
    const float* __restrict__ Wp, const float* __restrict__ x,
    short* __restrict__ WBt, short* __restrict__ Wot,
    short* __restrict__ xb) {
  int tid = threadIdx.x;
  if (blockIdx.z < 2) {
    const float* W = blockIdx.z ? Wo : Wv;
    short* Wt = blockIdx.z ? Wot : WBt;
    __shared__ float tile[64][65];
    int k0 = blockIdx.y * 64, n0 = blockIdx.x * 64;
#pragma unroll
    for (int i = 0; i < 4; ++i) {
      int idx = tid + i * 256;
      int r = idx >> 4, c4 = (idx & 15) * 4;
      float4 v = *(const float4*)&W[(size_t)(k0 + r) * D_ + n0 + c4];
      tile[r][c4 + 0] = v.x;
      tile[r][c4 + 1] = v.y;
      tile[r][c4 + 2] = v.z;
      tile[r][c4 + 3] = v.w;
    }
    __syncthreads();
#pragma unroll
    for (int j = 0; j < 2; ++j) {
      int idx = tid + j * 256;
      int n = idx >> 3, k8 = (idx & 7) * 8;
      s16x8 outv;
#pragma unroll
      for (int jj = 0; jj < 8; ++jj) outv[jj] = f2bf(tile[k8 + jj][n]);
      *(s16x8*)&Wt[(size_t)(n0 + n) * D_ + k0 + k8] = outv;
    }
  } else {
    int bid = blockIdx.y * 16 + blockIdx.x;  // 0..255
#pragma unroll
    for (int c = 0; c < 4; ++c) {
      size_t idx = (size_t)bid * 8192 + c * 2048 + tid * 8;
      float4 f0 = *(const float4*)&x[idx];
      float4 f1 = *(const float4*)&x[idx + 4];
      s16x8 v;
      v[0] = f2bf(f0.x); v[1] = f2bf(f0.y);
      v[2] = f2bf(f0.z); v[3] = f2bf(f0.w);
      v[4] = f2bf(f1.x); v[5] = f2bf(f1.y);
      v[6] = f2bf(f1.z); v[7] = f2bf(f1.w);
      *(s16x8*)&xb[idx] = v;
    }
    if (bid < 4) {  // Wp rows of WBt
#pragma unroll
      for (int it = 0; it < 8; ++it) {
        int item = bid * 2048 + it * 256 + tid;  // 0..8191
        int row = item >> 7, k8 = (item & 127) * 8;
        s16x8 v;
        if (row < H_ * DEPTH_) {
#pragma unroll
          for (int j = 0; j < 8; ++j)
            v[j] = f2bf(Wp[(size_t)(k8 + j) * (H_ * DEPTH_) + row]);
        } else {
#pragma unroll
          for (int j = 0; j < 8; ++j) v[j] = 0;
        }
        *(s16x8*)&WBt[(size_t)(1024 + row) * D_ + k8] = v;
      }
    }
  }
}

// -------------------------------------------------------------------------
// MFMA bf16 GEMM, 64x64 tile, BK=64 dbuf + counted vmcnt(4) (R3-proven),
// 1D grid + contiguous-chunk XCD swizzle (R6-proven). Unchanged from R6.
// -------------------------------------------------------------------------
template <int MODE, int NX>
__global__ __launch_bounds__(256) void gemm128(
    const short* __restrict__ A, const short* __restrict__ Bt,
    float* __restrict__ Cf, short* __restrict__ Vt,
    const float* __restrict__ bp, float* __restrict__ paths_t) {
  __shared__ short As[2][64 * 64];  // 2 x 8 KB
  __shared__ short Bs[2][64 * 64];  // 2 x 8 KB
  const int K = D_;
  int tid = threadIdx.x;
  int swz = xcd_swz(blockIdx.x, NX * 32);
  int bm = (swz / NX) << 6, bn = (swz % NX) << 6;
  int w = tid >> 6, lane = tid & 63;
  int wm = (w >> 1) * 32, wn = (w & 1) * 32;
  int g = lane >> 4, fr = lane & 15;
  f32x4 acc[2][2] = {};

  // staging source addressing: per 1KB chunk lane l covers row l>>3,
  // source colgroup (l&7)^(l>>3) (XOR swizzle, same for every chunk).
  int r8 = lane >> 3;
  int scg = (lane & 7) ^ r8;
  const short* Asrc[2];
  const short* Bsrc[2];
#pragma unroll
  for (int i = 0; i < 2; ++i) {
    Asrc[i] = A + (size_t)(bm + w * 16 + i * 8 + r8) * K + scg * 8;
    Bsrc[i] = Bt + (size_t)(bn + w * 16 + i * 8 + r8) * K + scg * 8;
  }

#define STAGE(BUF, K0)                                    \
  {                                                       \
    glds16(Asrc[0] + (K0), &As[BUF][(w * 16 + 0) * 64]);  \
    glds16(Asrc[1] + (K0), &As[BUF][(w * 16 + 8) * 64]);  \
    glds16(Bsrc[0] + (K0), &Bs[BUF][(w * 16 + 0) * 64]);  \
    glds16(Bsrc[1] + (K0), &Bs[BUF][(w * 16 + 8) * 64]);  \
  }

#define COMPUTE(BUF)                                                   \
  {                                                                    \
    _Pragma("unroll") for (int ks = 0; ks < 2; ++ks) {                 \
      int slot = ((ks * 4 + g) ^ (fr & 7)) * 8;                        \
      s16x8 a0 = *(const s16x8*)&As[BUF][(wm + fr) * 64 + slot];       \
      s16x8 a1 = *(const s16x8*)&As[BUF][(wm + 16 + fr) * 64 + slot];  \
      s16x8 b0 = *(const s16x8*)&Bs[BUF][(wn + fr) * 64 + slot];       \
      s16x8 b1 = *(const s16x8*)&Bs[BUF][(wn + 16 + fr) * 64 + slot];  \
      acc[0][0] = MFMA16(a0, b0, acc[0][0]);                           \
      acc[0][1] = MFMA16(a0, b1, acc[0][1]);                           \
      acc[1][0] = MFMA16(a1, b0, acc[1][0]);                           \
      acc[1][1] = MFMA16(a1, b1, acc[1][1]);                           \
    }                                                                  \
  }

  // K-loop: 16 K-steps of 64, dbuf, prefetch depth 1.
  // After STAGE(next): <=8 glds outstanding; vmcnt(4) -> cur tile landed.
  STAGE(0, 0);
  for (int kt = 0; kt < 16; kt += 2) {
    BARRIER();  // readers of buf1 (COMPUTE(1) of prev pair) done
    STAGE(1, (kt + 1) * 64);
    asm volatile("s_waitcnt vmcnt(4)" ::: "memory");  // tile kt landed
    BARRIER();
    COMPUTE(0);
    BARRIER();  // readers of buf0 done
    if (kt + 2 < 16) {
      STAGE(0, (kt + 2) * 64);
      asm volatile("s_waitcnt vmcnt(4)" ::: "memory");  // tile kt+1 landed
    } else {
      asm volatile("s_waitcnt vmcnt(0)" ::: "memory");
    }
    BARRIER();
    COMPUTE(1);
  }
#undef STAGE
#undef COMPUTE

  int col = lane & 15, rbase = (lane >> 4) * 4;
  if (MODE == 0) {
#pragma unroll
    for (int mi = 0; mi < 2; ++mi)
#pragma unroll
      for (int ni = 0; ni < 2; ++ni)
#pragma unroll
        for (int r = 0; r < 4; ++r)
          Cf[(size_t)(bm + wm + mi * 16 + rbase + r) * D_ + bn + wn +
             ni * 16 + col] = acc[mi][ni][r];
  } else if (bn < 1024) {
    // V epilogue: bf16, transposed [bh][dh][t]
#pragma unroll
    for (int mi = 0; mi < 2; ++mi)
#pragma unroll
      for (int ni = 0; ni < 2; ++ni) {
        int m = bm + wm + mi * 16 + rbase;  // t start (4 consecutive)
        int n = bn + wn + ni * 16 + col;    // dh col
        int b = m >> 10, t = m & (T_ - 1);
        int h = n >> 7, dh = n & (DH_ - 1);
        s16x4 v4;
#pragma unroll
        for (int r = 0; r < 4; ++r) v4[r] = f2bf(acc[mi][ni][r]);
        *(s16x4*)&Vt[((size_t)((b * H_ + h) * DH_ + dh)) * T_ + t] = v4;
      }
  } else {
    // paths epilogue: sigmoid(z + bp), fp32, (B,H,T,DEPTH)
#pragma unroll
    for (int ni = 0; ni < 2; ++ni) {
      int pn = wn + ni * 16 + col;  // 0..63
      if (pn < H_ * DEPTH_) {
        float bias = bp[pn];
        int h = pn / DEPTH_, d = pn % DEPTH_;
#pragma unroll
        for (int mi = 0; mi < 2; ++mi)
#pragma unroll
          for (int r = 0; r < 4; ++r) {
            int m = bm + wm + mi * 16 + rbase + r;
            int b = m >> 10, t = m & (T_ - 1);
            float pv = 1.f / (1.f + __expf(-(acc[mi][ni][r] + bias)));
            paths_t[(((size_t)(b * H_ + h) * T_ + t) * DEPTH_) + d] = pv;
          }
      }
    }
  }
}

// -------------------------------------------------------------------------
// Fused causal p-adic attention, MFMA P.V.  512 threads / 8 waves.
// KT=128: 9 k-tiles per block-pair (qt/4 + (31-qt)/4 + 2 == 9 for all qt).
// R6 glds-staged V (R7's direct-global read regressed) + NEW: DOUBLE-
// BUFFERED Vs with async prefetch and raw barriers. Key: Vs rows are
// WAVE-PRIVATE (wave w DMAs rows [16w,16w+16) and only its own PV reads
// them) -> V needs no cross-wave sync; only Ss does. So the pre-PV
// __syncthreads (vmcnt(0) drain, kills prefetch) becomes lgkmcnt(0) +
// raw s_barrier, and tile kt+1's glds stays in flight across PV.
// FIFO discipline: pk loads are issued BEFORE the prefetch, so the
// compiler's wait for pk consumption drains tile-kt's (older) glds while
// leaving kt+1's (newer) outstanding. LDS 74 KB @ 1 block/CU.
// SIM via packed fp32: agree = (2pq-1)*pk + (1-pq), packed over q-row pairs.
// -------------------------------------------------------------------------
#define LS2 136

__global__ __launch_bounds__(512) void attn_kernel(
    const float* __restrict__ paths_t, const short* __restrict__ Vt,
    short* __restrict__ ctxb) {
  int swz = xcd_swz(blockIdx.x, 256);
  int bh = swz >> 4;  // 0..15 (bh-major: 16 sharers contiguous)
  int bx = swz & 15;  // 0..15
  int b = bh >> 3, h = bh & 7;
  int w = threadIdx.x >> 6, lane = threadIdx.x & 63;
  int g = lane >> 4, fr = lane & 15;

  __shared__ short Vs[2][DH_ * 128];  // [buf][dh][k] swizzled, 2 x 32 KB
  __shared__ short Ss[32 * LS2];      // [q][k] padded 136, ~8.5 KB
  __shared__ float lsum_s[32];

  const float* pb = paths_t + (size_t)bh * T_ * DEPTH_;
  const short* vb = Vt + (size_t)bh * DH_ * T_;

  // glds addressing (per wave: 4 x 1KB covering rows w*16 .. w*16+15)
  int r4 = lane >> 4, cg = lane & 15;
  const short* Vsrc[4];
  int Vdo[4];
#pragma unroll
  for (int i = 0; i < 4; ++i) {
    int row = w * 16 + i * 4 + r4;
    int scol = (cg ^ (row & 15)) * 8;
    Vsrc[i] = vb + (size_t)row * T_ + scol;
    Vdo[i] = (w * 16 + i * 4) * 128;
  }

  for (int half = 0; half < 2; ++half) {
    int qt = half ? (31 - bx) : bx;
    int q0 = qt * 32;
    int nkt = (qt >> 2) + 1;  // KT=128 tiles; pair total = 9 always

    // per-half q-row coefficient pairs: agree = c1*pk + c0,
    // c1 = 2*pq-1, c0 = 1-pq, packed over (j0,j1) / (j2,j3).
    f32x2 c1_[2][DEPTH_], c0_[2][DEPTH_];
#pragma unroll
    for (int jp = 0; jp < 2; ++jp) {
      const float* qr0 = pb + (size_t)(q0 + w * 4 + jp * 2) * DEPTH_;
      const float* qr1 = qr0 + DEPTH_;
#pragma unroll
      for (int d = 0; d < DEPTH_; ++d) {
        float p0 = qr0[d], p1 = qr1[d];
        c1_[jp][d] = (f32x2){2.f * p0 - 1.f, 2.f * p1 - 1.f};
        c0_[jp][d] = (f32x2){1.f - p0, 1.f - p1};
      }
    }
    f32x4 acc[2] = {{0.f, 0.f, 0.f, 0.f}, {0.f, 0.f, 0.f, 0.f}};
    float part[4] = {};
    const f32x2 one2 = {1.f, 1.f};

    // prologue: async-prefetch tile 0 into buf 0 (wave-private rows)
#pragma unroll
    for (int i = 0; i < 4; ++i) glds16(Vsrc[i], &Vs[0][Vdo[i]]);

    for (int kt = 0; kt < nkt; ++kt) {
      int cur = kt & 1;
      int k0 = kt * 128;
      BARRIER();  // prev PV readers of Ss done -> safe to overwrite Ss
      // pk loads FIRST (older than next-tile prefetch in the vmcnt FIFO)
      int kA = k0 + lane, kB = k0 + 64 + lane;
      const float* krA = pb + (size_t)kA * DEPTH_;
      const float* krB = pb + (size_t)kB * DEPTH_;
      float pkA[DEPTH_], pkB[DEPTH_];
#pragma unroll
      for (int d = 0; d < DEPTH_; ++d) {
        pkA[d] = krA[d];
        pkB[d] = krB[d];
      }
      asm volatile("" ::: "memory");  // pin pk loads before the prefetch
      if (kt + 1 < nkt) {
#pragma unroll
        for (int i = 0; i < 4; ++i)
          glds16(Vsrc[i] + (kt + 1) * 128, &Vs[cur ^ 1][Vdo[i]]);
      }
      // splat k-path values into packed pairs
      f32x2 bkA[DEPTH_], bkB[DEPTH_];
#pragma unroll
      for (int d = 0; d < DEPTH_; ++d) {
        bkA[d] = (f32x2){pkA[d], pkA[d]};
        bkB[d] = (f32x2){pkB[d], pkB[d]};
      }
#pragma unroll
      for (int jp = 0; jp < 2; ++jp) {
        {  // column A (k = kA)
          f32x2 a0 = pk_fma2(c1_[jp][0], bkA[0], c0_[jp][0]);
          f32x2 a1 = pk_fma2(c1_[jp][1], bkA[1], c0_[jp][1]);
          f32x2 a2 = pk_fma2(c1_[jp][2], bkA[2], c0_[jp][2]);
          f32x2 a3 = pk_fma2(c1_[jp][3], bkA[3], c0_[jp][3]);
          f32x2 a4 = pk_fma2(c1_[jp][4], bkA[4], c0_[jp][4]);
          f32x2 t4 = pk_add2(a4, one2);
          f32x2 t3 = pk_fma2(a3, t4, one2);
          f32x2 t2 = pk_fma2(a2, t3, one2);
          f32x2 t1 = pk_fma2(a1, t2, one2);
          f32x2 s2 = pk_mul2(a0, t1);
#pragma unroll
          for (int jj = 0; jj < 2; ++jj) {
            int j = jp * 2 + jj;
            int qg = q0 + w * 4 + j;
            float wv = (kA <= qg) ? __expf(s2[jj] * 0.2f) : 0.f;
            part[j] += wv;
            Ss[(w * 4 + j) * LS2 + lane] = f2bf(wv);
          }
        }
        {  // column B (k = kB)
          f32x2 a0 = pk_fma2(c1_[jp][0], bkB[0], c0_[jp][0]);
          f32x2 a1 = pk_fma2(c1_[jp][1], bkB[1], c0_[jp][1]);
          f32x2 a2 = pk_fma2(c1_[jp][2], bkB[2], c0_[jp][2]);
          f32x2 a3 = pk_fma2(c1_[jp][3], bkB[3], c0_[jp][3]);
          f32x2 a4 = pk_fma2(c1_[jp][4], bkB[4], c0_[jp][4]);
          f32x2 t4 = pk_add2(a4, one2);
          f32x2 t3 = pk_fma2(a3, t4, one2);
          f32x2 t2 = pk_fma2(a2, t3, one2);
          f32x2 t1 = pk_fma2(a1, t2, one2);
          f32x2 s2 = pk_mul2(a0, t1);
#pragma unroll
          for (int jj = 0; jj < 2; ++jj) {
            int j = jp * 2 + jj;
            int qg = q0 + w * 4 + j;
            float wv = (kB <= qg) ? __expf(s2[jj] * 0.2f) : 0.f;
            part[j] += wv;
            Ss[(w * 4 + j) * LS2 + 64 + lane] = f2bf(wv);
          }
        }
      }
      // Ss visible to all waves; do NOT drain vmcnt (kt+1 prefetch in flight)
      asm volatile("s_waitcnt lgkmcnt(0)" ::: "memory");
      BARRIER();
      // PV: Ss cross-wave (barrier'd); Vs rows wave-private, tile kt's DMA
      // complete (FIFO: this tile's pk loads, newer than it, were consumed).
#pragma unroll
      for (int ks = 0; ks < 4; ++ks) {
        int ko = ks * 32 + g * 8;
        int sl = ((ks * 4 + g) ^ fr) * 8;  // swizzled Vs slot (row&15 == fr)
        s16x8 sa0 = *(const s16x8*)&Ss[fr * LS2 + ko];
        s16x8 sa1 = *(const s16x8*)&Ss[(16 + fr) * LS2 + ko];
        s16x8 vv = *(const s16x8*)&Vs[cur][(w * 16 + fr) * 128 + sl];
        acc[0] = MFMA16(sa0, vv, acc[0]);
        acc[1] = MFMA16(sa1, vv, acc[1]);
      }
    }
    // reduce per-q row sums across the wave's 64 lanes (each lane holds 2 k)
#pragma unroll
    for (int j = 0; j < 4; ++j) {
      float s = part[j];
#pragma unroll
      for (int off = 32; off >= 1; off >>= 1) s += __shfl_xor(s, off, 64);
      if (lane == j) lsum_s[w * 4 + j] = s;
    }
    __syncthreads();
    // epilogue: normalize, write bf16 ctx
    int col = fr, rbase = g * 4;
#pragma unroll
    for (int qt2 = 0; qt2 < 2; ++qt2)
#pragma unroll
      for (int r = 0; r < 4; ++r) {
        int ql = qt2 * 16 + rbase + r;
        int dh = w * 16 + col;
        float val = acc[qt2][r] / lsum_s[ql];
        ctxb[(size_t)(b * T_ + q0 + ql) * D_ + h * DH_ + dh] = f2bf(val);
      }
    __syncthreads();  // protect lsum_s before next half
  }
}

// -------------------------------------------------------------------------
extern "C" void kernel_launch(void* const* d_in, const int* in_sizes, int n_in,
                              void* d_out, int out_size, void* d_ws,
                              size_t ws_size, hipStream_t stream) {
  const float* x = (const float*)d_in[0];
  const float* Wp = (const float*)d_in[1];
  const float* bp = (const float*)d_in[2];
  const float* Wv = (const float*)d_in[3];
  const float* Wo = (const float*)d_in[4];
  float* out = (float*)d_out;

  char* ws = (char*)d_ws;
  float* paths_t = (float*)ws;           //   327,680 B
  short* Vt = (short*)(ws + 327680);     // 4,194,304 B bf16 [bh][dh][t]
  short* WBt = (short*)(ws + 4521984);   // 2,228,224 B bf16 [1088][1024]
  short* Wot = (short*)(ws + 6750208);   // 2,097,152 B bf16 [1024][1024]
  short* ctxb = (short*)(ws + 8847360);  // 4,194,304 B bf16 [2048][1024]
  short* xb = (short*)(ws + 13041664);   // 4,194,304 B bf16 [2048][1024]
  // total ~17.2 MB

  prep_kernel<<<dim3(16, 16, 3), 256, 0, stream>>>(Wv, Wo, Wp, x, WBt, Wot,
                                                   xb);
  gemm128<1, 17><<<dim3(17 * 32), 256, 0, stream>>>(xb, WBt, nullptr, Vt, bp,
                                                    paths_t);
  attn_kernel<<<dim3(256), 512, 0, stream>>>(paths_t, Vt, ctxb);
  gemm128<0, 16><<<dim3(16 * 32), 256, 0, stream>>>(ctxb, Wot, out, nullptr,
                                                    nullptr, nullptr);
}

// Round 9
// 120.993 us; speedup vs baseline: 1.0442x; 1.0200x over previous
//
#include <hip/hip_runtime.h>
#include <hip/hip_bf16.h>

#define B_ 2
#define T_ 1024
#define D_ 1024
#define H_ 8
#define DEPTH_ 5
#define DH_ 128

typedef short s16x8 __attribute__((ext_vector_type(8)));
typedef short s16x4 __attribute__((ext_vector_type(4)));
typedef float f32x4 __attribute__((ext_vector_type(4)));
typedef float f32x2 __attribute__((ext_vector_type(2)));

__device__ inline short f2bf(float f) {
  __hip_bfloat16 h = __float2bfloat16(f);
  return *reinterpret_cast<short*>(&h);
}

#define MFMA16(a, b, c) __builtin_amdgcn_mfma_f32_16x16x32_bf16(a, b, c, 0, 0, 0)

// packed fp32 (VOP3P, full-rate on gfx950): d = a*b+c / a*b / a+b per 32-bit half
__device__ __forceinline__ f32x2 pk_fma2(f32x2 a, f32x2 b, f32x2 c) {
  f32x2 d;
  asm("v_pk_fma_f32 %0, %1, %2, %3" : "=v"(d) : "v"(a), "v"(b), "v"(c));
  return d;
}
__device__ __forceinline__ f32x2 pk_mul2(f32x2 a, f32x2 b) {
  f32x2 d;
  asm("v_pk_mul_f32 %0, %1, %2" : "=v"(d) : "v"(a), "v"(b));
  return d;
}
__device__ __forceinline__ f32x2 pk_add2(f32x2 a, f32x2 b) {
  f32x2 d;
  asm("v_pk_add_f32 %0, %1, %2" : "=v"(d) : "v"(a), "v"(b));
  return d;
}

// global -> LDS async copy, 16B/lane. LDS dest = wave-uniform base + lane*16.
typedef __attribute__((address_space(3))) unsigned int lds_u32_t;
typedef __attribute__((address_space(1))) unsigned int glb_u32_t;
__device__ __forceinline__ void glds16(const void* g, void* l) {
  __builtin_amdgcn_global_load_lds((const glb_u32_t*)g, (lds_u32_t*)l, 16, 0,
                                   0);
}

// compiler fence + hw barrier (raw: does NOT drain vmcnt like __syncthreads)
#define BARRIER()                     \
  {                                   \
    asm volatile("" ::: "memory");    \
    __builtin_amdgcn_s_barrier();     \
    asm volatile("" ::: "memory");    \
  }

// contiguous-chunk XCD swizzle: consecutive logical ids stay on ONE XCD
// (dispatch round-robins blockIdx across the 8 XCDs). Requires nwg%8==0.
__device__ __forceinline__ int xcd_swz(int bid, int nwg) {
  int cpx = nwg >> 3;
  return (bid & 7) * cpx + (bid >> 3);
}

// -------------------------------------------------------------------------
// Prep (one launch, grid (16,16,3), 256 threads) — r6-proven form:
//  z=0: Wv[K][N] -> WBt rows 0..1023 (bf16 [n][k])
//  z=1: Wo -> Wot (bf16 [n][k])
//  z=2: x fp32 -> xb bf16 (streaming); blocks 0..3 also scatter
//       Wp[1024][40] -> WBt rows 1024..1087 (rows >=40 zeroed).
// Streaming / no inter-block reuse -> no swizzle (T1 transfer null).
// -------------------------------------------------------------------------
__global__ __launch_bounds__(256) void prep_kernel(
    const float* __restrict__ Wv, const float* __restrict__ Wo,
    const float* __restrict__ Wp, const float* __restrict__ x,
    short* __restrict__ WBt, short* __restrict__ Wot,
    short* __restrict__ xb) {
  int tid = threadIdx.x;
  if (blockIdx.z < 2) {
    const float* W = blockIdx.z ? Wo : Wv;
    short* Wt = blockIdx.z ? Wot : WBt;
    __shared__ float tile[64][65];
    int k0 = blockIdx.y * 64, n0 = blockIdx.x * 64;
#pragma unroll
    for (int i = 0; i < 4; ++i) {
      int idx = tid + i * 256;
      int r = idx >> 4, c4 = (idx & 15) * 4;
      float4 v = *(const float4*)&W[(size_t)(k0 + r) * D_ + n0 + c4];
      tile[r][c4 + 0] = v.x;
      tile[r][c4 + 1] = v.y;
      tile[r][c4 + 2] = v.z;
      tile[r][c4 + 3] = v.w;
    }
    __syncthreads();
#pragma unroll
    for (int j = 0; j < 2; ++j) {
      int idx = tid + j * 256;
      int n = idx >> 3, k8 = (idx & 7) * 8;
      s16x8 outv;
#pragma unroll
      for (int jj = 0; jj < 8; ++jj) outv[jj] = f2bf(tile[k8 + jj][n]);
      *(s16x8*)&Wt[(size_t)(n0 + n) * D_ + k0 + k8] = outv;
    }
  } else {
    int bid = blockIdx.y * 16 + blockIdx.x;  // 0..255
#pragma unroll
    for (int c = 0; c < 4; ++c) {
      size_t idx = (size_t)bid * 8192 + c * 2048 + tid * 8;
      float4 f0 = *(const float4*)&x[idx];
      float4 f1 = *(const float4*)&x[idx + 4];
      s16x8 v;
      v[0] = f2bf(f0.x); v[1] = f2bf(f0.y);
      v[2] = f2bf(f0.z); v[3] = f2bf(f0.w);
      v[4] = f2bf(f1.x); v[5] = f2bf(f1.y);
      v[6] = f2bf(f1.z); v[7] = f2bf(f1.w);
      *(s16x8*)&xb[idx] = v;
    }
    if (bid < 4) {  // Wp rows of WBt
#pragma unroll
      for (int it = 0; it < 8; ++it) {
        int item = bid * 2048 + it * 256 + tid;  // 0..8191
        int row = item >> 7, k8 = (item & 127) * 8;
        s16x8 v;
        if (row < H_ * DEPTH_) {
#pragma unroll
          for (int j = 0; j < 8; ++j)
            v[j] = f2bf(Wp[(size_t)(k8 + j) * (H_ * DEPTH_) + row]);
        } else {
#pragma unroll
          for (int j = 0; j < 8; ++j) v[j] = 0;
        }
        *(s16x8*)&WBt[(size_t)(1024 + row) * D_ + k8] = v;
      }
    }
  }
}

// -------------------------------------------------------------------------
// MFMA bf16 GEMM, 64x64 tile, BK=64 dbuf + counted vmcnt(4) (R3-proven),
// 1D grid + contiguous-chunk XCD swizzle (R6-proven). Unchanged from R6.
// -------------------------------------------------------------------------
template <int MODE, int NX>
__global__ __launch_bounds__(256) void gemm128(
    const short* __restrict__ A, const short* __restrict__ Bt,
    float* __restrict__ Cf, short* __restrict__ Vt,
    const float* __restrict__ bp, float* __restrict__ paths_t) {
  __shared__ short As[2][64 * 64];  // 2 x 8 KB
  __shared__ short Bs[2][64 * 64];  // 2 x 8 KB
  const int K = D_;
  int tid = threadIdx.x;
  int swz = xcd_swz(blockIdx.x, NX * 32);
  int bm = (swz / NX) << 6, bn = (swz % NX) << 6;
  int w = tid >> 6, lane = tid & 63;
  int wm = (w >> 1) * 32, wn = (w & 1) * 32;
  int g = lane >> 4, fr = lane & 15;
  f32x4 acc[2][2] = {};

  // staging source addressing: per 1KB chunk lane l covers row l>>3,
  // source colgroup (l&7)^(l>>3) (XOR swizzle, same for every chunk).
  int r8 = lane >> 3;
  int scg = (lane & 7) ^ r8;
  const short* Asrc[2];
  const short* Bsrc[2];
#pragma unroll
  for (int i = 0; i < 2; ++i) {
    Asrc[i] = A + (size_t)(bm + w * 16 + i * 8 + r8) * K + scg * 8;
    Bsrc[i] = Bt + (size_t)(bn + w * 16 + i * 8 + r8) * K + scg * 8;
  }

#define STAGE(BUF, K0)                                    \
  {                                                       \
    glds16(Asrc[0] + (K0), &As[BUF][(w * 16 + 0) * 64]);  \
    glds16(Asrc[1] + (K0), &As[BUF][(w * 16 + 8) * 64]);  \
    glds16(Bsrc[0] + (K0), &Bs[BUF][(w * 16 + 0) * 64]);  \
    glds16(Bsrc[1] + (K0), &Bs[BUF][(w * 16 + 8) * 64]);  \
  }

#define COMPUTE(BUF)                                                   \
  {                                                                    \
    _Pragma("unroll") for (int ks = 0; ks < 2; ++ks) {                 \
      int slot = ((ks * 4 + g) ^ (fr & 7)) * 8;                        \
      s16x8 a0 = *(const s16x8*)&As[BUF][(wm + fr) * 64 + slot];       \
      s16x8 a1 = *(const s16x8*)&As[BUF][(wm + 16 + fr) * 64 + slot];  \
      s16x8 b0 = *(const s16x8*)&Bs[BUF][(wn + fr) * 64 + slot];       \
      s16x8 b1 = *(const s16x8*)&Bs[BUF][(wn + 16 + fr) * 64 + slot];  \
      acc[0][0] = MFMA16(a0, b0, acc[0][0]);                           \
      acc[0][1] = MFMA16(a0, b1, acc[0][1]);                           \
      acc[1][0] = MFMA16(a1, b0, acc[1][0]);                           \
      acc[1][1] = MFMA16(a1, b1, acc[1][1]);                           \
    }                                                                  \
  }

  // K-loop: 16 K-steps of 64, dbuf, prefetch depth 1.
  // After STAGE(next): <=8 glds outstanding; vmcnt(4) -> cur tile landed.
  STAGE(0, 0);
  for (int kt = 0; kt < 16; kt += 2) {
    BARRIER();  // readers of buf1 (COMPUTE(1) of prev pair) done
    STAGE(1, (kt + 1) * 64);
    asm volatile("s_waitcnt vmcnt(4)" ::: "memory");  // tile kt landed
    BARRIER();
    COMPUTE(0);
    BARRIER();  // readers of buf0 done
    if (kt + 2 < 16) {
      STAGE(0, (kt + 2) * 64);
      asm volatile("s_waitcnt vmcnt(4)" ::: "memory");  // tile kt+1 landed
    } else {
      asm volatile("s_waitcnt vmcnt(0)" ::: "memory");
    }
    BARRIER();
    COMPUTE(1);
  }
#undef STAGE
#undef COMPUTE

  int col = lane & 15, rbase = (lane >> 4) * 4;
  if (MODE == 0) {
#pragma unroll
    for (int mi = 0; mi < 2; ++mi)
#pragma unroll
      for (int ni = 0; ni < 2; ++ni)
#pragma unroll
        for (int r = 0; r < 4; ++r)
          Cf[(size_t)(bm + wm + mi * 16 + rbase + r) * D_ + bn + wn +
             ni * 16 + col] = acc[mi][ni][r];
  } else if (bn < 1024) {
    // V epilogue: bf16, transposed [bh][dh][t]
#pragma unroll
    for (int mi = 0; mi < 2; ++mi)
#pragma unroll
      for (int ni = 0; ni < 2; ++ni) {
        int m = bm + wm + mi * 16 + rbase;  // t start (4 consecutive)
        int n = bn + wn + ni * 16 + col;    // dh col
        int b = m >> 10, t = m & (T_ - 1);
        int h = n >> 7, dh = n & (DH_ - 1);
        s16x4 v4;
#pragma unroll
        for (int r = 0; r < 4; ++r) v4[r] = f2bf(acc[mi][ni][r]);
        *(s16x4*)&Vt[((size_t)((b * H_ + h) * DH_ + dh)) * T_ + t] = v4;
      }
  } else {
    // paths epilogue: sigmoid(z + bp), fp32, (B,H,T,DEPTH)
#pragma unroll
    for (int ni = 0; ni < 2; ++ni) {
      int pn = wn + ni * 16 + col;  // 0..63
      if (pn < H_ * DEPTH_) {
        float bias = bp[pn];
        int h = pn / DEPTH_, d = pn % DEPTH_;
#pragma unroll
        for (int mi = 0; mi < 2; ++mi)
#pragma unroll
          for (int r = 0; r < 4; ++r) {
            int m = bm + wm + mi * 16 + rbase + r;
            int b = m >> 10, t = m & (T_ - 1);
            float pv = 1.f / (1.f + __expf(-(acc[mi][ni][r] + bias)));
            paths_t[(((size_t)(b * H_ + h) * T_ + t) * DEPTH_) + d] = pv;
          }
      }
    }
  }
}

// -------------------------------------------------------------------------
// Fused causal p-adic attention, MFMA P.V.  512 threads / 8 waves.
// KT=128: 9 k-tiles per block-pair (qt/4 + (31-qt)/4 + 2 == 9 for all qt).
// R6-proven form (best raw 122.9 / best normalized 34.1): glds-staged
// single-buffer Vs (R7 direct-global and R8 dbuf both regressed),
// bh-major contiguous-chunk XCD swizzle (Vt slice L2-resident).
// V tile staged via global_load_lds into unpadded Vs[128][128] with XOR
// source swizzle (conflict-free DMA writes, 2-way frag reads).
// SIM via packed fp32: agree = (2pq-1)*pk + (1-pq), packed over q-row pairs.
// -------------------------------------------------------------------------
#define LS2 136

__global__ __launch_bounds__(512) void attn_kernel(
    const float* __restrict__ paths_t, const short* __restrict__ Vt,
    short* __restrict__ ctxb) {
  int swz = xcd_swz(blockIdx.x, 256);
  int bh = swz >> 4;  // 0..15 (bh-major: 16 sharers contiguous)
  int bx = swz & 15;  // 0..15
  int b = bh >> 3, h = bh & 7;
  int w = threadIdx.x >> 6, lane = threadIdx.x & 63;
  int g = lane >> 4, fr = lane & 15;

  __shared__ short Vs[DH_ * 128];  // [dh][k] unpadded+swizzled, 32 KB
  __shared__ short Ss[32 * LS2];   // [q][k] padded 136, ~8.5 KB
  __shared__ float lsum_s[32];

  const float* pb = paths_t + (size_t)bh * T_ * DEPTH_;
  const short* vb = Vt + (size_t)bh * DH_ * T_;

  // glds addressing (per wave: 4 x 1KB covering rows w*16 .. w*16+15)
  int r4 = lane >> 4, cg = lane & 15;
  const short* Vsrc[4];
  short* Vdst[4];
#pragma unroll
  for (int i = 0; i < 4; ++i) {
    int row = w * 16 + i * 4 + r4;
    int scol = (cg ^ (row & 15)) * 8;
    Vsrc[i] = vb + (size_t)row * T_ + scol;
    Vdst[i] = &Vs[(w * 16 + i * 4) * 128];
  }

  for (int half = 0; half < 2; ++half) {
    int qt = half ? (31 - bx) : bx;
    int q0 = qt * 32;
    int nkt = (qt >> 2) + 1;  // KT=128 tiles; pair total = 9 always

    // per-half q-row coefficient pairs: agree = c1*pk + c0,
    // c1 = 2*pq-1, c0 = 1-pq, packed over (j0,j1) / (j2,j3).
    f32x2 c1_[2][DEPTH_], c0_[2][DEPTH_];
#pragma unroll
    for (int jp = 0; jp < 2; ++jp) {
      const float* qr0 = pb + (size_t)(q0 + w * 4 + jp * 2) * DEPTH_;
      const float* qr1 = qr0 + DEPTH_;
#pragma unroll
      for (int d = 0; d < DEPTH_; ++d) {
        float p0 = qr0[d], p1 = qr1[d];
        c1_[jp][d] = (f32x2){2.f * p0 - 1.f, 2.f * p1 - 1.f};
        c0_[jp][d] = (f32x2){1.f - p0, 1.f - p1};
      }
    }
    f32x4 acc[2] = {{0.f, 0.f, 0.f, 0.f}, {0.f, 0.f, 0.f, 0.f}};
    float part[4] = {};
    const f32x2 one2 = {1.f, 1.f};

    for (int kt = 0; kt < nkt; ++kt) {
      int k0 = kt * 128;
      __syncthreads();  // prev MFMA readers / epilogue done
      // key-path loads first (oldest in vmcnt queue -> sim doesn't wait on glds)
      int kA = k0 + lane, kB = k0 + 64 + lane;
      const float* krA = pb + (size_t)kA * DEPTH_;
      const float* krB = pb + (size_t)kB * DEPTH_;
      float pkA[DEPTH_], pkB[DEPTH_];
#pragma unroll
      for (int d = 0; d < DEPTH_; ++d) {
        pkA[d] = krA[d];
        pkB[d] = krB[d];
      }
      // V tile DMA: 8 waves x 4 glds = 32 KB
#pragma unroll
      for (int i = 0; i < 4; ++i) glds16(Vsrc[i] + k0, Vdst[i]);
      // splat k-path values into packed pairs
      f32x2 bkA[DEPTH_], bkB[DEPTH_];
#pragma unroll
      for (int d = 0; d < DEPTH_; ++d) {
        bkA[d] = (f32x2){pkA[d], pkA[d]};
        bkB[d] = (f32x2){pkB[d], pkB[d]};
      }
#pragma unroll
      for (int jp = 0; jp < 2; ++jp) {
        {  // column A (k = kA)
          f32x2 a0 = pk_fma2(c1_[jp][0], bkA[0], c0_[jp][0]);
          f32x2 a1 = pk_fma2(c1_[jp][1], bkA[1], c0_[jp][1]);
          f32x2 a2 = pk_fma2(c1_[jp][2], bkA[2], c0_[jp][2]);
          f32x2 a3 = pk_fma2(c1_[jp][3], bkA[3], c0_[jp][3]);
          f32x2 a4 = pk_fma2(c1_[jp][4], bkA[4], c0_[jp][4]);
          f32x2 t4 = pk_add2(a4, one2);
          f32x2 t3 = pk_fma2(a3, t4, one2);
          f32x2 t2 = pk_fma2(a2, t3, one2);
          f32x2 t1 = pk_fma2(a1, t2, one2);
          f32x2 s2 = pk_mul2(a0, t1);
#pragma unroll
          for (int jj = 0; jj < 2; ++jj) {
            int j = jp * 2 + jj;
            int qg = q0 + w * 4 + j;
            float wv = (kA <= qg) ? __expf(s2[jj] * 0.2f) : 0.f;
            part[j] += wv;
            Ss[(w * 4 + j) * LS2 + lane] = f2bf(wv);
          }
        }
        {  // column B (k = kB)
          f32x2 a0 = pk_fma2(c1_[jp][0], bkB[0], c0_[jp][0]);
          f32x2 a1 = pk_fma2(c1_[jp][1], bkB[1], c0_[jp][1]);
          f32x2 a2 = pk_fma2(c1_[jp][2], bkB[2], c0_[jp][2]);
          f32x2 a3 = pk_fma2(c1_[jp][3], bkB[3], c0_[jp][3]);
          f32x2 a4 = pk_fma2(c1_[jp][4], bkB[4], c0_[jp][4]);
          f32x2 t4 = pk_add2(a4, one2);
          f32x2 t3 = pk_fma2(a3, t4, one2);
          f32x2 t2 = pk_fma2(a2, t3, one2);
          f32x2 t1 = pk_fma2(a1, t2, one2);
          f32x2 s2 = pk_mul2(a0, t1);
#pragma unroll
          for (int jj = 0; jj < 2; ++jj) {
            int j = jp * 2 + jj;
            int qg = q0 + w * 4 + j;
            float wv = (kB <= qg) ? __expf(s2[jj] * 0.2f) : 0.f;
            part[j] += wv;
            Ss[(w * 4 + j) * LS2 + 64 + lane] = f2bf(wv);
          }
        }
      }
      __syncthreads();  // drains vmcnt (glds) + lgkm (Ss writes)
      // P @ V via MFMA: wave covers dh [16*w, 16*w+16); 4 ks steps of k32
#pragma unroll
      for (int ks = 0; ks < 4; ++ks) {
        int ko = ks * 32 + g * 8;
        int sl = ((ks * 4 + g) ^ fr) * 8;  // swizzled Vs slot (row&15 == fr)
        s16x8 sa0 = *(const s16x8*)&Ss[fr * LS2 + ko];
        s16x8 sa1 = *(const s16x8*)&Ss[(16 + fr) * LS2 + ko];
        s16x8 vv = *(const s16x8*)&Vs[(w * 16 + fr) * 128 + sl];
        acc[0] = MFMA16(sa0, vv, acc[0]);
        acc[1] = MFMA16(sa1, vv, acc[1]);
      }
    }
    // reduce per-q row sums across the wave's 64 lanes (each lane holds 2 k)
#pragma unroll
    for (int j = 0; j < 4; ++j) {
      float s = part[j];
#pragma unroll
      for (int off = 32; off >= 1; off >>= 1) s += __shfl_xor(s, off, 64);
      if (lane == j) lsum_s[w * 4 + j] = s;
    }
    __syncthreads();
    // epilogue: normalize, write bf16 ctx
    int col = fr, rbase = g * 4;
#pragma unroll
    for (int qt2 = 0; qt2 < 2; ++qt2)
#pragma unroll
      for (int r = 0; r < 4; ++r) {
        int ql = qt2 * 16 + rbase + r;
        int dh = w * 16 + col;
        float val = acc[qt2][r] / lsum_s[ql];
        ctxb[(size_t)(b * T_ + q0 + ql) * D_ + h * DH_ + dh] = f2bf(val);
      }
    __syncthreads();  // protect lsum_s before next half
  }
}

// -------------------------------------------------------------------------
extern "C" void kernel_launch(void* const* d_in, const int* in_sizes, int n_in,
                              void* d_out, int out_size, void* d_ws,
                              size_t ws_size, hipStream_t stream) {
  const float* x = (const float*)d_in[0];
  const float* Wp = (const float*)d_in[1];
  const float* bp = (const float*)d_in[2];
  const float* Wv = (const float*)d_in[3];
  const float* Wo = (const float*)d_in[4];
  float* out = (float*)d_out;

  char* ws = (char*)d_ws;
  float* paths_t = (float*)ws;           //   327,680 B
  short* Vt = (short*)(ws + 327680);     // 4,194,304 B bf16 [bh][dh][t]
  short* WBt = (short*)(ws + 4521984);   // 2,228,224 B bf16 [1088][1024]
  short* Wot = (short*)(ws + 6750208);   // 2,097,152 B bf16 [1024][1024]
  short* ctxb = (short*)(ws + 8847360);  // 4,194,304 B bf16 [2048][1024]
  short* xb = (short*)(ws + 13041664);   // 4,194,304 B bf16 [2048][1024]
  // total ~17.2 MB

  prep_kernel<<<dim3(16, 16, 3), 256, 0, stream>>>(Wv, Wo, Wp, x, WBt, Wot,
                                                   xb);
  gemm128<1, 17><<<dim3(17 * 32), 256, 0, stream>>>(xb, WBt, nullptr, Vt, bp,
                                                    paths_t);
  attn_kernel<<<dim3(256), 512, 0, stream>>>(paths_t, Vt, ctxb);
  gemm128<0, 16><<<dim3(16 * 32), 256, 0, stream>>>(ctxb, Wot, out, nullptr,
                                                    nullptr, nullptr);
}